// Round 2
// baseline (1428.206 us; speedup 1.0000x reference)
//
#include <hip/hip_runtime.h>
#include <cstdint>
#include <cmath>

#define BT 8192   // tokens
#define DD 1024   // model dim
#define HH 4096   // hidden dim
#define EE 8      // experts
#define MTMAX 136 // max m-tiles over all experts: 16384/128 + 7 partials, padded

typedef __attribute__((ext_vector_type(8))) short short8;
typedef __attribute__((ext_vector_type(4))) float f32x4;
typedef unsigned short u16;
typedef unsigned int u32;

// round-to-nearest-even fp32 -> bf16 (inputs are finite; no NaN path needed)
__device__ __forceinline__ u16 f2bf(float f) {
    u32 u = __float_as_uint(f);
    u += 0x7FFFu + ((u >> 16) & 1u);
    return (u16)(u >> 16);
}

// async global->LDS, 16B per lane; LDS dest is wave-uniform base + lane*16
__device__ __forceinline__ void gld_lds16(const void* g, void* l) {
    __builtin_amdgcn_global_load_lds((__attribute__((address_space(1))) void*)g,
                                     (__attribute__((address_space(3))) void*)l,
                                     16, 0, 0);
}

// ---------------- fp32 -> bf16 bulk convert (8 elems/thread) ----------------
__global__ void cvt_kernel(const float* __restrict__ src, u16* __restrict__ dst, int n8) {
    int i = blockIdx.x * blockDim.x + threadIdx.x;
    if (i >= n8) return;
    size_t base = (size_t)i * 8;
    float4 a = *(const float4*)(src + base);
    float4 b = *(const float4*)(src + base + 4);
    uint4 o;
    o.x = (u32)f2bf(a.x) | ((u32)f2bf(a.y) << 16);
    o.y = (u32)f2bf(a.z) | ((u32)f2bf(a.w) << 16);
    o.z = (u32)f2bf(b.x) | ((u32)f2bf(b.y) << 16);
    o.w = (u32)f2bf(b.z) | ((u32)f2bf(b.w) << 16);
    *(uint4*)(dst + base) = o;
}

// ---------------- gating: fp64 logits, top-2, softmax, build lists ----------
__global__ void gating_kernel(const float* __restrict__ x, const float* __restrict__ wg,
                              float* __restrict__ gate_arr, int* __restrict__ list,
                              int* __restrict__ info,
                              int* __restrict__ counts, float* __restrict__ importance) {
    int wave = (blockIdx.x * blockDim.x + threadIdx.x) >> 6;  // one wave per token
    int lane = threadIdx.x & 63;
    if (wave >= BT) return;
    const float* xr = x + (size_t)wave * DD;
    double acc[EE];
#pragma unroll
    for (int e = 0; e < EE; ++e) acc[e] = 0.0;
#pragma unroll
    for (int c = 0; c < DD / 256; ++c) {    // float4-vectorized, fp64 accumulate
        const int i = c * 256 + lane * 4;
        float4 xv = *(const float4*)(xr + i);
        double x0 = xv.x, x1 = xv.y, x2 = xv.z, x3 = xv.w;
#pragma unroll
        for (int e = 0; e < EE; ++e) {
            float4 wv = *(const float4*)(wg + e * DD + i);
            acc[e] += x0 * (double)wv.x + x1 * (double)wv.y
                    + x2 * (double)wv.z + x3 * (double)wv.w;
        }
    }
#pragma unroll
    for (int e = 0; e < EE; ++e) {
        double v = acc[e];
        for (int off = 32; off; off >>= 1) v += __shfl_down(v, off, 64);
        acc[e] = v;  // lane 0 holds the sum
    }
    if (lane == 0) {
        int i0 = 0; double v0 = acc[0];
        for (int e = 1; e < EE; ++e) if (acc[e] > v0) { v0 = acc[e]; i0 = e; }
        int i1 = -1; double v1 = -1e300;
        for (int e = 0; e < EE; ++e) { if (e == i0) continue; if (acc[e] > v1) { v1 = acc[e]; i1 = e; } }
        double e1 = exp(v1 - v0);
        double s = 1.0 + e1;
        float g0 = (float)(1.0 / s);
        float g1 = (float)(e1 / s);
        gate_arr[2 * wave]     = g0;
        gate_arr[2 * wave + 1] = g1;
        atomicAdd(&importance[i0], g0);
        atomicAdd(&importance[i1], g1);
        int p0 = atomicAdd(&counts[i0], 1);
        list[i0 * BT + p0] = wave;                 // token id
        int p1 = atomicAdd(&counts[i1], 1);
        list[i1 * BT + p1] = wave;
        info[2 * wave]     = (i0 << 16) | p0;      // (expert, position-in-list)
        info[2 * wave + 1] = (i1 << 16) | p1;
    }
}

// loss = 0.01*(cv^2(importance)+cv^2(load)); exclusive scan; dense tile map --
__global__ void loss_kernel(const int* __restrict__ counts, const float* __restrict__ importance,
                            int* __restrict__ offs, float* __restrict__ out_loss,
                            int* __restrict__ tmap, int* __restrict__ ntiles) {
    if (threadIdx.x == 0 && blockIdx.x == 0) {
        double mi = 0, ml = 0;
        int off = 0;
        for (int e = 0; e < EE; e++) {
            offs[e] = off; off += counts[e];
            mi += (double)importance[e]; ml += (double)counts[e];
        }
        mi /= EE; ml /= EE;
        double vi = 0, vl = 0;
        for (int e = 0; e < EE; e++) {
            double di = (double)importance[e] - mi; vi += di * di;
            double dl = (double)counts[e] - ml;     vl += dl * dl;
        }
        vi /= (EE - 1); vl /= (EE - 1);
        double cv_i = vi / (mi * mi + 1e-10);
        double cv_l = vl / (ml * ml + 1e-10);
        *out_loss = (float)((cv_i + cv_l) * 0.01);
        // dense M-tile map shared by both GEMMs (BM=128 rows of the packed layout)
        int ntl = 0;
        for (int e = 0; e < EE; e++)
            for (int t = 0; t < counts[e]; t += 128)
                tmap[ntl++] = (e << 20) | t;       // (expert, mbase-within-expert)
        *ntiles = ntl;                              // <= 135
    }
}

// ------- gather x token rows into packed expert-major bf16 layout -----------
__global__ void gather_x_kernel(const float* __restrict__ x, const int* __restrict__ list,
                                const int* __restrict__ counts, const int* __restrict__ offs,
                                u16* __restrict__ xg) {
    int r = blockIdx.x;   // packed row, 0..2*BT-1
    int e = 0;
#pragma unroll
    for (int i = 1; i < EE; ++i) if (r >= offs[i]) e = i;
    int m = r - offs[e];
    if (m >= counts[e]) return;  // defensive; sum of counts == 2*BT
    int token = list[e * BT + m];
    const float* src = x + (size_t)token * DD;
    u16* dst = xg + (size_t)r * DD;
    int i = threadIdx.x * 4;
    float4 a = *(const float4*)(src + i);
    uint2 o;
    o.x = (u32)f2bf(a.x) | ((u32)f2bf(a.y) << 16);
    o.y = (u32)f2bf(a.z) | ((u32)f2bf(a.w) << 16);
    *(uint2*)(dst + i) = o;
}

// ----------- packed-row MFMA GEMM, depth-3 counted-vmcnt pipeline -----------
// C[m,n] = sum_k A[row(m), k] * W[e][n, k]  (both K-contiguous, NT layout)
// Grid: 1-D dense tile map. XCD-chunked bijective swizzle + SUPERTILE order
// within each chunk (8 m-tiles x C columns): the ~64 concurrent blocks/XCD
// share 8 A-panels + C B-panels (<=3 MB, fits 4 MB L2) -> most staging loads
// become L2 hits instead of LLC misses.
// K-loop (T3+T4): 4 static LDS buffers, prologue stages 3 tiles (12 loads in
// flight), each step: s_waitcnt vmcnt(8) [tile t landed] -> raw s_barrier ->
// stage tile t+3 -> compute tile t. vmcnt never drains to 0 until the tail,
// so loads get ~3 compute phases to cover LLC/HBM latency.
// Race audit: every wave's vmcnt(8) precedes its barrier, so post-barrier all
// waves' quarters of tile t are in LDS; all ds_reads of a buffer complete
// before their consuming MFMAs, which precede the next "memory"-clobbered
// wait -> re-staging that buffer 3 steps later cannot race.
template <int K, int NT, bool GELU, bool GATHER>
__global__ __launch_bounds__(256) void moe_gemm(const u16* __restrict__ Asrc,
                                                const u16* __restrict__ Bsrc,
                                                const float* __restrict__ bias,
                                                const int* __restrict__ list,
                                                const int* __restrict__ counts,
                                                const int* __restrict__ offs,
                                                const int* __restrict__ tmap,
                                                const int* __restrict__ ntiles,
                                                u16* __restrict__ outB,
                                                float* __restrict__ outF) {
    constexpr int NXT = NT / 128;          // n-tiles: 32 (GEMM1) / 8 (GEMM2)
    constexpr int C = NXT / 8;             // columns per XCD chunk: 4 / 1
    constexpr int q = C * MTMAX;           // blocks per XCD chunk: 544 / 136
    const int bid = blockIdx.x;            // nwg = 8*q, %8 == 0 by construction
    const int xcd = bid & 7;
    const int j = bid >> 3;                // [0, q)
    const int st = j / (8 * C);            // supertile row group
    const int w = j - st * 8 * C;
    const int nt = xcd * C + (w >> 3);     // this XCD's column
    const int mt = st * 8 + (w & 7);       // m-tile within supertile
    if (mt >= *ntiles) return;             // only pad tiles die here
    const int ent = tmap[mt];
    const int e = ent >> 20;
    const int mbase = ent & 0xFFFFF;
    const int cnt = counts[e];
    const int mmax = cnt - mbase;          // valid rows in this tile (>=1)
    const int rowbase = offs[e] + mbase;   // packed output row base
    const int nbase = nt * 128;
    const int tid = threadIdx.x;
    const int lane = tid & 63;
    const int wv = tid >> 6;

    // LDS tiles in 16B-chunk layout: chunk c = kchunk*128 + row  (conflict-free
    // for both global_load_lds (lane-contiguous) and ds_read_b128 frag reads).
    // 4 static buffers (compile-time indices) = 64 KiB -> 2 blocks/CU; the
    // depth-3 in-block prefetch replaces the lost inter-block overlap.
    __shared__ u16 As[4][128 * 32];
    __shared__ u16 Bs[4][128 * 32];
    __shared__ int rows_lds[128];

    if constexpr (GATHER) {
        if (tid < 128) {
            int m = min(tid, mmax - 1);
            rows_lds[tid] = list[e * BT + mbase + m];
        }
        __syncthreads();   // also drains the list[] vmem loads -> vmcnt == 0
    }

    const int myrow = tid & 127;          // row of my two chunks
    const int kch = tid >> 7;             // kchunk 0/1; second chunk is +2
    size_t arow;
    if constexpr (GATHER) arow = (size_t)rows_lds[myrow];
    else                  arow = (size_t)(rowbase + min(myrow, mmax - 1));
    const u16* aptr = Asrc + arow * (size_t)K + kch * 8;
    const u16* bptr = Bsrc + ((size_t)e * NT + nbase + myrow) * (size_t)K + kch * 8;

    f32x4 acc[4][4] = {};
    const int moff = (wv >> 1) * 64;
    const int noff = (wv & 1) * 64;
    const int kq = lane >> 4;
    const int rsub = lane & 15;

#define STAGE(bi, k0)                                            \
    do {                                                         \
        gld_lds16(aptr + (k0),      &As[bi][tid * 8]);           \
        gld_lds16(aptr + (k0) + 16, &As[bi][(tid + 256) * 8]);   \
        gld_lds16(bptr + (k0),      &Bs[bi][tid * 8]);           \
        gld_lds16(bptr + (k0) + 16, &Bs[bi][(tid + 256) * 8]);   \
    } while (0)

#define COMPUTE(bi)                                                                   \
    do {                                                                              \
        short8 af[4], bfr[4];                                                         \
        _Pragma("unroll")                                                             \
        for (int mi = 0; mi < 4; mi++)                                                \
            af[mi] = *(const short8*)&As[bi][(kq * 128 + moff + mi * 16 + rsub) * 8]; \
        _Pragma("unroll")                                                             \
        for (int ni = 0; ni < 4; ni++)                                                \
            bfr[ni] = *(const short8*)&Bs[bi][(kq * 128 + noff + ni * 16 + rsub) * 8];\
        _Pragma("unroll")                                                             \
        for (int mi = 0; mi < 4; mi++)                                                \
            _Pragma("unroll")                                                         \
            for (int ni = 0; ni < 4; ni++)                                            \
                acc[mi][ni] = __builtin_amdgcn_mfma_f32_16x16x32_bf16(                 \
                    af[mi], bfr[ni], acc[mi][ni], 0, 0, 0);                           \
    } while (0)

// One pipeline step: wait for tile tt (counted, never 0 until tail), barrier,
// stage tile tt+3 into the buffer freed at step tt-1, compute tile tt.
#define PHASE(cb, sb, tt)                                            \
    do {                                                             \
        if ((tt) + 3 < NSTEPS) {                                     \
            asm volatile("s_waitcnt vmcnt(8)" ::: "memory");         \
            __builtin_amdgcn_s_barrier();                            \
            STAGE(sb, ((tt) + 3) * 32);                              \
        } else if ((tt) + 2 < NSTEPS) {                              \
            asm volatile("s_waitcnt vmcnt(8)" ::: "memory");         \
            __builtin_amdgcn_s_barrier();                            \
        } else if ((tt) + 1 < NSTEPS) {                              \
            asm volatile("s_waitcnt vmcnt(4)" ::: "memory");         \
            __builtin_amdgcn_s_barrier();                            \
        } else {                                                     \
            asm volatile("s_waitcnt vmcnt(0)" ::: "memory");         \
            __builtin_amdgcn_s_barrier();                            \
        }                                                            \
        COMPUTE(cb);                                                 \
    } while (0)

    constexpr int NSTEPS = K / 32;         // 32 (GEMM1) / 128 (GEMM2), %4 == 0
    STAGE(0, 0);
    STAGE(1, 32);
    STAGE(2, 64);                          // 12 loads in flight
    for (int t = 0; t < NSTEPS; t += 4) {
        PHASE(0, 3, t);
        PHASE(1, 0, t + 1);
        PHASE(2, 1, t + 2);
        PHASE(3, 2, t + 3);
    }
#undef PHASE
#undef STAGE
#undef COMPUTE

    // epilogue: C/D layout col = lane&15, row = (lane>>4)*4 + reg  [m89-verified]
    const int rq = (lane >> 4) * 4;
    float bvals[4];
#pragma unroll
    for (int ni = 0; ni < 4; ni++)
        bvals[ni] = bias[(size_t)e * NT + nbase + noff + ni * 16 + rsub];
#pragma unroll
    for (int mi = 0; mi < 4; mi++) {
#pragma unroll
        for (int r = 0; r < 4; r++) {
            int m = moff + mi * 16 + rq + r;
            if (m < mmax) {
                size_t ro = (size_t)(rowbase + m);
#pragma unroll
                for (int ni = 0; ni < 4; ni++) {
                    int n = nbase + noff + ni * 16 + rsub;
                    float v = acc[mi][ni][r] + bvals[ni];
                    if constexpr (GELU) {
                        v = 0.5f * v * (1.0f + erff(v * 0.7071067811865476f));  // exact gelu
                        outB[ro * NT + n] = f2bf(v);
                    } else {
                        outF[ro * NT + n] = v;
                    }
                }
            }
        }
    }
}

// ---------------- softmax over D for both slots + weighted combine + log ----
__global__ void combine_kernel(const float* __restrict__ o, const float* __restrict__ gates,
                               const int* __restrict__ info, const int* __restrict__ offs,
                               float* __restrict__ y) {
    const int b = blockIdx.x;
    const int tid = threadIdx.x;
    const int lane = tid & 63, wv = tid >> 6;
    const int inf0 = info[2 * b], inf1 = info[2 * b + 1];
    const int r0i = offs[inf0 >> 16] + (inf0 & 0xffff);
    const int r1i = offs[inf1 >> 16] + (inf1 & 0xffff);
    const float* r0 = o + (size_t)r0i * DD;
    const float* r1 = o + (size_t)r1i * DD;
    float v0[4], v1[4];
#pragma unroll
    for (int j = 0; j < 4; j++) { v0[j] = r0[tid + 256 * j]; v1[j] = r1[tid + 256 * j]; }
    float m0 = fmaxf(fmaxf(v0[0], v0[1]), fmaxf(v0[2], v0[3]));
    float m1 = fmaxf(fmaxf(v1[0], v1[1]), fmaxf(v1[2], v1[3]));
#pragma unroll
    for (int off = 32; off; off >>= 1) {
        m0 = fmaxf(m0, __shfl_xor(m0, off, 64));
        m1 = fmaxf(m1, __shfl_xor(m1, off, 64));
    }
    __shared__ float sred[2][4];
    if (lane == 0) { sred[0][wv] = m0; sred[1][wv] = m1; }
    __syncthreads();
    m0 = fmaxf(fmaxf(sred[0][0], sred[0][1]), fmaxf(sred[0][2], sred[0][3]));
    m1 = fmaxf(fmaxf(sred[1][0], sred[1][1]), fmaxf(sred[1][2], sred[1][3]));
    float p0[4], p1[4], s0 = 0.f, s1 = 0.f;
#pragma unroll
    for (int j = 0; j < 4; j++) {
        p0[j] = expf(v0[j] - m0); s0 += p0[j];
        p1[j] = expf(v1[j] - m1); s1 += p1[j];
    }
#pragma unroll
    for (int off = 32; off; off >>= 1) {
        s0 += __shfl_xor(s0, off, 64);
        s1 += __shfl_xor(s1, off, 64);
    }
    __shared__ float sred2[2][4];
    if (lane == 0) { sred2[0][wv] = s0; sred2[1][wv] = s1; }
    __syncthreads();
    s0 = sred2[0][0] + sred2[0][1] + sred2[0][2] + sred2[0][3];
    s1 = sred2[1][0] + sred2[1][1] + sred2[1][2] + sred2[1][3];
    const float c0 = gates[2 * b] / s0;
    const float c1 = gates[2 * b + 1] / s1;
#pragma unroll
    for (int j = 0; j < 4; j++) {
        float c = p0[j] * c0 + p1[j] * c1;
        if (c == 0.f) c = 2.2204460492503131e-16f;  // np.finfo(float64).eps
        y[(size_t)b * DD + tid + 256 * j] = logf(c);
    }
}

extern "C" void kernel_launch(void* const* d_in, const int* in_sizes, int n_in,
                              void* d_out, int out_size, void* d_ws, size_t ws_size,
                              hipStream_t stream) {
    const float* x     = (const float*)d_in[0];
    const float* wgate = (const float*)d_in[1];
    const float* fc1w  = (const float*)d_in[2];
    const float* fc1b  = (const float*)d_in[3];
    const float* fc2w  = (const float*)d_in[4];
    const float* fc2b  = (const float*)d_in[5];
    float* out = (float*)d_out;

    char* ws = (char*)d_ws;
    const size_t MB = 1024 * 1024;
    // big layout (289 MiB): [0,64) w1b (later o fp32, exactly 64 MiB)
    //                       [64,128) w2b; [128,256) h bf16 packed; [256,288) xg; meta@288
    // small layout (273 MiB): [0,64) w1b/o; [64,128) w2b; [128,144) xb; [144,272) h; meta@272
    const bool big = ws_size >= 289 * MB;
    u16* w1b = (u16*)(ws);
    float* o = (float*)(ws);
    u16* w2b = (u16*)(ws + 64 * MB);
    u16* xb  = (u16*)(ws + 128 * MB);              // small path only
    u16* h   = (u16*)(ws + (big ? 128 : 144) * MB);
    u16* xg  = (u16*)(ws + 256 * MB);              // big path only
    char* meta = ws + (big ? 288 : 272) * MB;
    int* counts       = (int*)meta;                 // 32 B
    int* offs         = (int*)(meta + 32);          // 32 B
    float* importance = (float*)(meta + 64);        // 32 B
    int* ntiles       = (int*)(meta + 96);          // 4 B (written by loss_kernel)
    float* gate_arr   = (float*)(meta + 128);       // 64 KiB
    int* info         = (int*)(meta + 128 + 65536); // 64 KiB
    int* list         = (int*)(meta + 128 + 131072);// 256 KiB
    int* tmap         = (int*)(meta + 512 * 1024);  // 544 B

    hipMemsetAsync(meta, 0, 96, stream);  // counts + offs + importance
    cvt_kernel<<<(EE * HH * DD / 8 + 255) / 256, 256, 0, stream>>>(fc1w, w1b, EE * HH * DD / 8);
    cvt_kernel<<<(EE * DD * HH / 8 + 255) / 256, 256, 0, stream>>>(fc2w, w2b, EE * DD * HH / 8);
    gating_kernel<<<BT / 4, 256, 0, stream>>>(x, wgate, gate_arr, list, info, counts, importance);
    loss_kernel<<<1, 64, 0, stream>>>(counts, importance, offs, out + (size_t)BT * DD, tmap, ntiles);

    if (big) {
        gather_x_kernel<<<2 * BT, 256, 0, stream>>>(x, list, counts, offs, xg);
        moe_gemm<DD, HH, true, false><<<(HH / 128) * MTMAX, 256, 0, stream>>>(
            xg, w1b, fc1b, nullptr, counts, offs, tmap, ntiles, h, nullptr);
    } else {
        cvt_kernel<<<(BT * DD / 8 + 255) / 256, 256, 0, stream>>>(x, xb, BT * DD / 8);
        moe_gemm<DD, HH, true, true><<<(HH / 128) * MTMAX, 256, 0, stream>>>(
            xb, w1b, fc1b, list, counts, offs, tmap, ntiles, h, nullptr);
    }
    // pass B: o = h @ fc2_w^T + fc2_b ; A rows contiguous (packed), o packed.
    moe_gemm<HH, DD, false, false><<<(DD / 128) * MTMAX, 256, 0, stream>>>(
        h, w2b, fc2b, nullptr, counts, offs, tmap, ntiles, nullptr, o);
    combine_kernel<<<BT, 256, 0, stream>>>(o, gate_arr, info, offs, out);
}

// Round 3
// 1307.958 us; speedup vs baseline: 1.0919x; 1.0919x over previous
//
#include <hip/hip_runtime.h>
#include <cstdint>
#include <cmath>

#define BT 8192   // tokens
#define DD 1024   // model dim
#define HH 4096   // hidden dim
#define EE 8      // experts
#define MT2 72    // max 256-row m-tiles: 16384/256 + 7 partials, padded to 72

typedef __attribute__((ext_vector_type(8))) short short8;
typedef __attribute__((ext_vector_type(4))) float f32x4;
typedef unsigned short u16;
typedef unsigned int u32;

// round-to-nearest-even fp32 -> bf16 (inputs are finite; no NaN path needed)
__device__ __forceinline__ u16 f2bf(float f) {
    u32 u = __float_as_uint(f);
    u += 0x7FFFu + ((u >> 16) & 1u);
    return (u16)(u >> 16);
}

// async global->LDS, 16B per lane; LDS dest is wave-uniform base + lane*16
__device__ __forceinline__ void gld_lds16(const void* g, void* l) {
    __builtin_amdgcn_global_load_lds((__attribute__((address_space(1))) void*)g,
                                     (__attribute__((address_space(3))) void*)l,
                                     16, 0, 0);
}

// ---------------- fp32 -> bf16 bulk convert (8 elems/thread) ----------------
__global__ void cvt_kernel(const float* __restrict__ src, u16* __restrict__ dst, int n8) {
    int i = blockIdx.x * blockDim.x + threadIdx.x;
    if (i >= n8) return;
    size_t base = (size_t)i * 8;
    float4 a = *(const float4*)(src + base);
    float4 b = *(const float4*)(src + base + 4);
    uint4 o;
    o.x = (u32)f2bf(a.x) | ((u32)f2bf(a.y) << 16);
    o.y = (u32)f2bf(a.z) | ((u32)f2bf(a.w) << 16);
    o.z = (u32)f2bf(b.x) | ((u32)f2bf(b.y) << 16);
    o.w = (u32)f2bf(b.z) | ((u32)f2bf(b.w) << 16);
    *(uint4*)(dst + base) = o;
}

// ---------------- gating: fp64 logits, top-2, softmax, build lists ----------
__global__ void gating_kernel(const float* __restrict__ x, const float* __restrict__ wg,
                              float* __restrict__ gate_arr, int* __restrict__ list,
                              int* __restrict__ info,
                              int* __restrict__ counts, float* __restrict__ importance) {
    int wave = (blockIdx.x * blockDim.x + threadIdx.x) >> 6;  // one wave per token
    int lane = threadIdx.x & 63;
    if (wave >= BT) return;
    const float* xr = x + (size_t)wave * DD;
    double acc[EE];
#pragma unroll
    for (int e = 0; e < EE; ++e) acc[e] = 0.0;
#pragma unroll
    for (int c = 0; c < DD / 256; ++c) {    // float4-vectorized, fp64 accumulate
        const int i = c * 256 + lane * 4;
        float4 xv = *(const float4*)(xr + i);
        double x0 = xv.x, x1 = xv.y, x2 = xv.z, x3 = xv.w;
#pragma unroll
        for (int e = 0; e < EE; ++e) {
            float4 wv = *(const float4*)(wg + e * DD + i);
            acc[e] += x0 * (double)wv.x + x1 * (double)wv.y
                    + x2 * (double)wv.z + x3 * (double)wv.w;
        }
    }
#pragma unroll
    for (int e = 0; e < EE; ++e) {
        double v = acc[e];
        for (int off = 32; off; off >>= 1) v += __shfl_down(v, off, 64);
        acc[e] = v;  // lane 0 holds the sum
    }
    if (lane == 0) {
        int i0 = 0; double v0 = acc[0];
        for (int e = 1; e < EE; ++e) if (acc[e] > v0) { v0 = acc[e]; i0 = e; }
        int i1 = -1; double v1 = -1e300;
        for (int e = 0; e < EE; ++e) { if (e == i0) continue; if (acc[e] > v1) { v1 = acc[e]; i1 = e; } }
        double e1 = exp(v1 - v0);
        double s = 1.0 + e1;
        float g0 = (float)(1.0 / s);
        float g1 = (float)(e1 / s);
        gate_arr[2 * wave]     = g0;
        gate_arr[2 * wave + 1] = g1;
        atomicAdd(&importance[i0], g0);
        atomicAdd(&importance[i1], g1);
        int p0 = atomicAdd(&counts[i0], 1);
        list[i0 * BT + p0] = wave;                 // token id
        int p1 = atomicAdd(&counts[i1], 1);
        list[i1 * BT + p1] = wave;
        info[2 * wave]     = (i0 << 16) | p0;      // (expert, position-in-list)
        info[2 * wave + 1] = (i1 << 16) | p1;
    }
}

// loss = 0.01*(cv^2(importance)+cv^2(load)); exclusive scan; dense tile map --
__global__ void loss_kernel(const int* __restrict__ counts, const float* __restrict__ importance,
                            int* __restrict__ offs, float* __restrict__ out_loss,
                            int* __restrict__ tmap, int* __restrict__ ntiles) {
    if (threadIdx.x == 0 && blockIdx.x == 0) {
        double mi = 0, ml = 0;
        int off = 0;
        for (int e = 0; e < EE; e++) {
            offs[e] = off; off += counts[e];
            mi += (double)importance[e]; ml += (double)counts[e];
        }
        mi /= EE; ml /= EE;
        double vi = 0, vl = 0;
        for (int e = 0; e < EE; e++) {
            double di = (double)importance[e] - mi; vi += di * di;
            double dl = (double)counts[e] - ml;     vl += dl * dl;
        }
        vi /= (EE - 1); vl /= (EE - 1);
        double cv_i = vi / (mi * mi + 1e-10);
        double cv_l = vl / (ml * ml + 1e-10);
        *out_loss = (float)((cv_i + cv_l) * 0.01);
        // dense 256-row M-tile map shared by both GEMMs
        int ntl = 0;
        for (int e = 0; e < EE; e++)
            for (int t = 0; t < counts[e]; t += 256)
                tmap[ntl++] = (e << 20) | t;       // (expert, mbase-within-expert)
        *ntiles = ntl;                              // <= 71
    }
}

// ------- gather x token rows into packed expert-major bf16 layout -----------
__global__ void gather_x_kernel(const float* __restrict__ x, const int* __restrict__ list,
                                const int* __restrict__ counts, const int* __restrict__ offs,
                                u16* __restrict__ xg) {
    int r = blockIdx.x;   // packed row, 0..2*BT-1
    int e = 0;
#pragma unroll
    for (int i = 1; i < EE; ++i) if (r >= offs[i]) e = i;
    int m = r - offs[e];
    if (m >= counts[e]) return;  // defensive; sum of counts == 2*BT
    int token = list[e * BT + m];
    const float* src = x + (size_t)token * DD;
    u16* dst = xg + (size_t)r * DD;
    int i = threadIdx.x * 4;
    float4 a = *(const float4*)(src + i);
    uint2 o;
    o.x = (u32)f2bf(a.x) | ((u32)f2bf(a.y) << 16);
    o.y = (u32)f2bf(a.z) | ((u32)f2bf(a.w) << 16);
    *(uint2*)(dst + i) = o;
}

// ------------- packed-row MFMA GEMM, 256x256 tile, 2-barrier loop -----------
// C[m,n] = sum_k A[row(m), k] * W[e][n, k]  (both K-contiguous, NT layout)
// 512 threads = 8 waves (2M x 4N), per-wave output 128x64, acc[8][4] f32x4.
// Per 32-K step: stage 32 KB (A 16K + B 16K), 256 wave-MFMAs -> 8 MFMA/KB,
// 2x the arithmetic intensity of the 128^2 tile; per-SIMD MFMA time per step
// (~600 cy at 2 blocks/CU) covers an L2/LLC-latency stage, which the
// 2-barrier schedule exposes. LDS 65 KB -> 2 blocks/CU = 16 waves (same
// wave count as the 128^2 config, double the work per staged byte).
// Fragment loads / MFMA / epilogue are the round-1-verified code with
// 128->256 strides; LDS chunk layout (c = kchunk*256 + row) stays
// conflict-free for gld_lds (lane-contiguous) and ds_read_b128 frag reads.
template <int K, int NT, bool GELU, bool GATHER>
__global__ __launch_bounds__(512) void moe_gemm(const u16* __restrict__ Asrc,
                                                const u16* __restrict__ Bsrc,
                                                const float* __restrict__ bias,
                                                const int* __restrict__ list,
                                                const int* __restrict__ counts,
                                                const int* __restrict__ offs,
                                                const int* __restrict__ tmap,
                                                const int* __restrict__ ntiles,
                                                u16* __restrict__ outB,
                                                float* __restrict__ outF) {
    constexpr int NXT = NT / 256;          // n-tiles: 16 (GEMM1) / 4 (GEMM2)
    constexpr int nwg = NXT * MT2;         // 1152 / 288, both %8 == 0
    constexpr int q = nwg / 8;
    const int bid = blockIdx.x;
    const int wg = (bid & 7) * q + (bid >> 3);   // bijective XCD-chunked swizzle
    const int nt = wg / MT2;               // chunk covers contiguous m within a column
    const int mt = wg - nt * MT2;
    if (mt >= *ntiles) return;             // only pad tiles die here
    const int ent = tmap[mt];
    const int e = ent >> 20;
    const int mbase = ent & 0xFFFFF;
    const int cnt = counts[e];
    const int mmax = cnt - mbase;          // valid rows in this tile (>=1)
    const int rowbase = offs[e] + mbase;   // packed output row base
    const int nbase = nt * 256;
    const int tid = threadIdx.x;
    const int lane = tid & 63;
    const int wv = tid >> 6;               // 0..7

    __shared__ u16 As0[256 * 32], As1[256 * 32];
    __shared__ u16 Bs0[256 * 32], Bs1[256 * 32];
    __shared__ int rows_lds[256];

    if constexpr (GATHER) {
        if (tid < 256) {
            int m = min(tid, mmax - 1);
            rows_lds[tid] = list[e * BT + mbase + m];
        }
        __syncthreads();
    }

    const int myrow = tid & 255;          // row of my chunks
    const int kch = tid >> 8;             // kchunk 0/1; second chunk is +2
    size_t arow;
    if constexpr (GATHER) arow = (size_t)rows_lds[myrow];
    else                  arow = (size_t)(rowbase + min(myrow, mmax - 1));
    const u16* aptr = Asrc + arow * (size_t)K + kch * 8;
    const u16* bptr = Bsrc + ((size_t)e * NT + nbase + myrow) * (size_t)K + kch * 8;

    f32x4 acc[8][4] = {};
    const int moff = (wv >> 2) * 128;      // 2 M-wave-rows
    const int noff = (wv & 3) * 64;        // 4 N-wave-cols
    const int kq = lane >> 4;
    const int rsub = lane & 15;

#define STAGE(Ad, Bd, k0)                                              \
    do {                                                               \
        gld_lds16(aptr + (k0),      &(Ad)[(kch * 256 + myrow) * 8]);   \
        gld_lds16(aptr + (k0) + 16, &(Ad)[((kch + 2) * 256 + myrow) * 8]); \
        gld_lds16(bptr + (k0),      &(Bd)[(kch * 256 + myrow) * 8]);   \
        gld_lds16(bptr + (k0) + 16, &(Bd)[((kch + 2) * 256 + myrow) * 8]); \
    } while (0)

#define COMPUTE(Ad, Bd)                                                              \
    do {                                                                             \
        short8 af[8], bfr[4];                                                        \
        _Pragma("unroll")                                                            \
        for (int mi = 0; mi < 8; mi++)                                               \
            af[mi] = *(const short8*)&(Ad)[(kq * 256 + moff + mi * 16 + rsub) * 8];  \
        _Pragma("unroll")                                                            \
        for (int ni = 0; ni < 4; ni++)                                               \
            bfr[ni] = *(const short8*)&(Bd)[(kq * 256 + noff + ni * 16 + rsub) * 8]; \
        _Pragma("unroll")                                                            \
        for (int mi = 0; mi < 8; mi++)                                               \
            _Pragma("unroll")                                                        \
            for (int ni = 0; ni < 4; ni++)                                           \
                acc[mi][ni] = __builtin_amdgcn_mfma_f32_16x16x32_bf16(                \
                    af[mi], bfr[ni], acc[mi][ni], 0, 0, 0);                          \
    } while (0)

    STAGE(As0, Bs0, 0);
    __syncthreads();                        // buf0 staged (vmcnt drain + barrier)
    for (int k0 = 0; k0 < K; k0 += 64) {    // K % 64 == 0 (1024, 4096)
        STAGE(As1, Bs1, k0 + 32);           // prefetch next 32-K tile
        COMPUTE(As0, Bs0);
        __syncthreads();                    // next tile landed; reads of buf0 done
        if (k0 + 64 < K) STAGE(As0, Bs0, k0 + 64);
        COMPUTE(As1, Bs1);
        __syncthreads();
    }
#undef STAGE
#undef COMPUTE

    // epilogue: C/D layout col = lane&15, row = (lane>>4)*4 + reg  [m89-verified]
    const int rq = (lane >> 4) * 4;
    float bvals[4];
#pragma unroll
    for (int ni = 0; ni < 4; ni++)
        bvals[ni] = bias[(size_t)e * NT + nbase + noff + ni * 16 + rsub];
#pragma unroll
    for (int mi = 0; mi < 8; mi++) {
#pragma unroll
        for (int r = 0; r < 4; r++) {
            int m = moff + mi * 16 + rq + r;
            if (m < mmax) {
                size_t ro = (size_t)(rowbase + m);
#pragma unroll
                for (int ni = 0; ni < 4; ni++) {
                    int n = nbase + noff + ni * 16 + rsub;
                    float v = acc[mi][ni][r] + bvals[ni];
                    if constexpr (GELU) {
                        v = 0.5f * v * (1.0f + erff(v * 0.7071067811865476f));  // exact gelu
                        outB[ro * NT + n] = f2bf(v);
                    } else {
                        outF[ro * NT + n] = v;
                    }
                }
            }
        }
    }
}

// ---------------- softmax over D for both slots + weighted combine + log ----
__global__ void combine_kernel(const float* __restrict__ o, const float* __restrict__ gates,
                               const int* __restrict__ info, const int* __restrict__ offs,
                               float* __restrict__ y) {
    const int b = blockIdx.x;
    const int tid = threadIdx.x;
    const int lane = tid & 63, wv = tid >> 6;
    const int inf0 = info[2 * b], inf1 = info[2 * b + 1];
    const int r0i = offs[inf0 >> 16] + (inf0 & 0xffff);
    const int r1i = offs[inf1 >> 16] + (inf1 & 0xffff);
    const float* r0 = o + (size_t)r0i * DD;
    const float* r1 = o + (size_t)r1i * DD;
    float v0[4], v1[4];
#pragma unroll
    for (int j = 0; j < 4; j++) { v0[j] = r0[tid + 256 * j]; v1[j] = r1[tid + 256 * j]; }
    float m0 = fmaxf(fmaxf(v0[0], v0[1]), fmaxf(v0[2], v0[3]));
    float m1 = fmaxf(fmaxf(v1[0], v1[1]), fmaxf(v1[2], v1[3]));
#pragma unroll
    for (int off = 32; off; off >>= 1) {
        m0 = fmaxf(m0, __shfl_xor(m0, off, 64));
        m1 = fmaxf(m1, __shfl_xor(m1, off, 64));
    }
    __shared__ float sred[2][4];
    if (lane == 0) { sred[0][wv] = m0; sred[1][wv] = m1; }
    __syncthreads();
    m0 = fmaxf(fmaxf(sred[0][0], sred[0][1]), fmaxf(sred[0][2], sred[0][3]));
    m1 = fmaxf(fmaxf(sred[1][0], sred[1][1]), fmaxf(sred[1][2], sred[1][3]));
    float p0[4], p1[4], s0 = 0.f, s1 = 0.f;
#pragma unroll
    for (int j = 0; j < 4; j++) {
        p0[j] = expf(v0[j] - m0); s0 += p0[j];
        p1[j] = expf(v1[j] - m1); s1 += p1[j];
    }
#pragma unroll
    for (int off = 32; off; off >>= 1) {
        s0 += __shfl_xor(s0, off, 64);
        s1 += __shfl_xor(s1, off, 64);
    }
    __shared__ float sred2[2][4];
    if (lane == 0) { sred2[0][wv] = s0; sred2[1][wv] = s1; }
    __syncthreads();
    s0 = sred2[0][0] + sred2[0][1] + sred2[0][2] + sred2[0][3];
    s1 = sred2[1][0] + sred2[1][1] + sred2[1][2] + sred2[1][3];
    const float c0 = gates[2 * b] / s0;
    const float c1 = gates[2 * b + 1] / s1;
#pragma unroll
    for (int j = 0; j < 4; j++) {
        float c = p0[j] * c0 + p1[j] * c1;
        if (c == 0.f) c = 2.2204460492503131e-16f;  // np.finfo(float64).eps
        y[(size_t)b * DD + tid + 256 * j] = logf(c);
    }
}

extern "C" void kernel_launch(void* const* d_in, const int* in_sizes, int n_in,
                              void* d_out, int out_size, void* d_ws, size_t ws_size,
                              hipStream_t stream) {
    const float* x     = (const float*)d_in[0];
    const float* wgate = (const float*)d_in[1];
    const float* fc1w  = (const float*)d_in[2];
    const float* fc1b  = (const float*)d_in[3];
    const float* fc2w  = (const float*)d_in[4];
    const float* fc2b  = (const float*)d_in[5];
    float* out = (float*)d_out;

    char* ws = (char*)d_ws;
    const size_t MB = 1024 * 1024;
    // big layout (289 MiB): [0,64) w1b (later o fp32, exactly 64 MiB)
    //                       [64,128) w2b; [128,256) h bf16 packed; [256,288) xg; meta@288
    // small layout (273 MiB): [0,64) w1b/o; [64,128) w2b; [128,144) xb; [144,272) h; meta@272
    const bool big = ws_size >= 289 * MB;
    u16* w1b = (u16*)(ws);
    float* o = (float*)(ws);
    u16* w2b = (u16*)(ws + 64 * MB);
    u16* xb  = (u16*)(ws + 128 * MB);              // small path only
    u16* h   = (u16*)(ws + (big ? 128 : 144) * MB);
    u16* xg  = (u16*)(ws + 256 * MB);              // big path only
    char* meta = ws + (big ? 288 : 272) * MB;
    int* counts       = (int*)meta;                 // 32 B
    int* offs         = (int*)(meta + 32);          // 32 B
    float* importance = (float*)(meta + 64);        // 32 B
    int* ntiles       = (int*)(meta + 96);          // 4 B (written by loss_kernel)
    float* gate_arr   = (float*)(meta + 128);       // 64 KiB
    int* info         = (int*)(meta + 128 + 65536); // 64 KiB
    int* list         = (int*)(meta + 128 + 131072);// 256 KiB
    int* tmap         = (int*)(meta + 512 * 1024);  // 288 B

    hipMemsetAsync(meta, 0, 96, stream);  // counts + offs + importance
    cvt_kernel<<<(EE * HH * DD / 8 + 255) / 256, 256, 0, stream>>>(fc1w, w1b, EE * HH * DD / 8);
    cvt_kernel<<<(EE * DD * HH / 8 + 255) / 256, 256, 0, stream>>>(fc2w, w2b, EE * DD * HH / 8);
    gating_kernel<<<BT / 4, 256, 0, stream>>>(x, wgate, gate_arr, list, info, counts, importance);
    loss_kernel<<<1, 64, 0, stream>>>(counts, importance, offs, out + (size_t)BT * DD, tmap, ntiles);

    if (big) {
        gather_x_kernel<<<2 * BT, 256, 0, stream>>>(x, list, counts, offs, xg);
        moe_gemm<DD, HH, true, false><<<(HH / 256) * MT2, 512, 0, stream>>>(
            xg, w1b, fc1b, nullptr, counts, offs, tmap, ntiles, h, nullptr);
    } else {
        cvt_kernel<<<(BT * DD / 8 + 255) / 256, 256, 0, stream>>>(x, xb, BT * DD / 8);
        moe_gemm<DD, HH, true, true><<<(HH / 256) * MT2, 512, 0, stream>>>(
            xb, w1b, fc1b, list, counts, offs, tmap, ntiles, h, nullptr);
    }
    // pass B: o = h @ fc2_w^T + fc2_b ; A rows contiguous (packed), o packed.
    moe_gemm<HH, DD, false, false><<<(DD / 256) * MT2, 512, 0, stream>>>(
        h, w2b, fc2b, nullptr, counts, offs, tmap, ntiles, nullptr, o);
    combine_kernel<<<BT, 256, 0, stream>>>(o, gate_arr, info, offs, out);
}

// Round 5
// 1149.690 us; speedup vs baseline: 1.2423x; 1.1377x over previous
//
#include <hip/hip_runtime.h>
#include <cstdint>
#include <cmath>

#define BT 8192   // tokens
#define DD 1024   // model dim
#define HH 4096   // hidden dim
#define EE 8      // experts
#define MT2 72    // max 256-row m-tiles: 16384/256 + 7 partials, padded to 72

typedef __attribute__((ext_vector_type(8))) short short8;
typedef __attribute__((ext_vector_type(4))) float f32x4;
typedef unsigned short u16;
typedef unsigned int u32;

// round-to-nearest-even fp32 -> bf16 (inputs are finite; no NaN path needed)
__device__ __forceinline__ u16 f2bf(float f) {
    u32 u = __float_as_uint(f);
    u += 0x7FFFu + ((u >> 16) & 1u);
    return (u16)(u >> 16);
}

// async global->LDS, 16B per lane; LDS dest is wave-uniform base + lane*16
__device__ __forceinline__ void gld_lds16(const void* g, void* l) {
    __builtin_amdgcn_global_load_lds((__attribute__((address_space(1))) void*)g,
                                     (__attribute__((address_space(3))) void*)l,
                                     16, 0, 0);
}

// ---------------- fp32 -> bf16 bulk convert (8 elems/thread) ----------------
__global__ void cvt_kernel(const float* __restrict__ src, u16* __restrict__ dst, int n8) {
    int i = blockIdx.x * blockDim.x + threadIdx.x;
    if (i >= n8) return;
    size_t base = (size_t)i * 8;
    float4 a = *(const float4*)(src + base);
    float4 b = *(const float4*)(src + base + 4);
    uint4 o;
    o.x = (u32)f2bf(a.x) | ((u32)f2bf(a.y) << 16);
    o.y = (u32)f2bf(a.z) | ((u32)f2bf(a.w) << 16);
    o.z = (u32)f2bf(b.x) | ((u32)f2bf(b.y) << 16);
    o.w = (u32)f2bf(b.z) | ((u32)f2bf(b.w) << 16);
    *(uint4*)(dst + base) = o;
}

// ---------------- gating: fp64 logits, top-2, softmax, build lists ----------
__global__ void gating_kernel(const float* __restrict__ x, const float* __restrict__ wg,
                              float* __restrict__ gate_arr, int* __restrict__ list,
                              int* __restrict__ info,
                              int* __restrict__ counts, float* __restrict__ importance) {
    int wave = (blockIdx.x * blockDim.x + threadIdx.x) >> 6;  // one wave per token
    int lane = threadIdx.x & 63;
    if (wave >= BT) return;
    const float* xr = x + (size_t)wave * DD;
    double acc[EE];
#pragma unroll
    for (int e = 0; e < EE; ++e) acc[e] = 0.0;
#pragma unroll
    for (int c = 0; c < DD / 256; ++c) {    // float4-vectorized, fp64 accumulate
        const int i = c * 256 + lane * 4;
        float4 xv = *(const float4*)(xr + i);
        double x0 = xv.x, x1 = xv.y, x2 = xv.z, x3 = xv.w;
#pragma unroll
        for (int e = 0; e < EE; ++e) {
            float4 wv = *(const float4*)(wg + e * DD + i);
            acc[e] += x0 * (double)wv.x + x1 * (double)wv.y
                    + x2 * (double)wv.z + x3 * (double)wv.w;
        }
    }
#pragma unroll
    for (int e = 0; e < EE; ++e) {
        double v = acc[e];
        for (int off = 32; off; off >>= 1) v += __shfl_down(v, off, 64);
        acc[e] = v;  // lane 0 holds the sum
    }
    if (lane == 0) {
        int i0 = 0; double v0 = acc[0];
        for (int e = 1; e < EE; ++e) if (acc[e] > v0) { v0 = acc[e]; i0 = e; }
        int i1 = -1; double v1 = -1e300;
        for (int e = 0; e < EE; ++e) { if (e == i0) continue; if (acc[e] > v1) { v1 = acc[e]; i1 = e; } }
        double e1 = exp(v1 - v0);
        double s = 1.0 + e1;
        float g0 = (float)(1.0 / s);
        float g1 = (float)(e1 / s);
        gate_arr[2 * wave]     = g0;
        gate_arr[2 * wave + 1] = g1;
        atomicAdd(&importance[i0], g0);
        atomicAdd(&importance[i1], g1);
        int p0 = atomicAdd(&counts[i0], 1);
        list[i0 * BT + p0] = wave;                 // token id
        int p1 = atomicAdd(&counts[i1], 1);
        list[i1 * BT + p1] = wave;
        info[2 * wave]     = (i0 << 16) | p0;      // (expert, position-in-list)
        info[2 * wave + 1] = (i1 << 16) | p1;
    }
}

// loss = 0.01*(cv^2(importance)+cv^2(load)); exclusive scan; dense tile map --
__global__ void loss_kernel(const int* __restrict__ counts, const float* __restrict__ importance,
                            int* __restrict__ offs, float* __restrict__ out_loss,
                            int* __restrict__ tmap, int* __restrict__ ntiles) {
    if (threadIdx.x == 0 && blockIdx.x == 0) {
        double mi = 0, ml = 0;
        int off = 0;
        for (int e = 0; e < EE; e++) {
            offs[e] = off; off += counts[e];
            mi += (double)importance[e]; ml += (double)counts[e];
        }
        mi /= EE; ml /= EE;
        double vi = 0, vl = 0;
        for (int e = 0; e < EE; e++) {
            double di = (double)importance[e] - mi; vi += di * di;
            double dl = (double)counts[e] - ml;     vl += dl * dl;
        }
        vi /= (EE - 1); vl /= (EE - 1);
        double cv_i = vi / (mi * mi + 1e-10);
        double cv_l = vl / (ml * ml + 1e-10);
        *out_loss = (float)((cv_i + cv_l) * 0.01);
        // dense 256-row M-tile map shared by both GEMMs
        int ntl = 0;
        for (int e = 0; e < EE; e++)
            for (int t = 0; t < counts[e]; t += 256)
                tmap[ntl++] = (e << 20) | t;       // (expert, mbase-within-expert)
        *ntiles = ntl;                              // <= 71
    }
}

// ------- gather x token rows into packed expert-major bf16 layout -----------
__global__ void gather_x_kernel(const float* __restrict__ x, const int* __restrict__ list,
                                const int* __restrict__ counts, const int* __restrict__ offs,
                                u16* __restrict__ xg) {
    int r = blockIdx.x;   // packed row, 0..2*BT-1
    int e = 0;
#pragma unroll
    for (int i = 1; i < EE; ++i) if (r >= offs[i]) e = i;
    int m = r - offs[e];
    if (m >= counts[e]) return;  // defensive; sum of counts == 2*BT
    int token = list[e * BT + m];
    const float* src = x + (size_t)token * DD;
    u16* dst = xg + (size_t)r * DD;
    int i = threadIdx.x * 4;
    float4 a = *(const float4*)(src + i);
    uint2 o;
    o.x = (u32)f2bf(a.x) | ((u32)f2bf(a.y) << 16);
    o.y = (u32)f2bf(a.z) | ((u32)f2bf(a.w) << 16);
    *(uint2*)(dst + i) = o;
}

// ========== packed-row MFMA GEMM, 256x256 tile, 8-phase counted-vmcnt =======
// m201-template port. 512 thr = 8 waves. Per 64-K tile: 4 quadrant-phases,
// all 8 waves compute one 128x128 C-quadrant (64x32 strip each, 16 MFMA).
// LDS: 2 dbuf x {A,B} x 2 halves x (128x64 bf16) = 128 KiB EXACTLY (m201-
// proven static LDS size; round-4's extra rows_lds pushed past it, removed).
// Stage stream (1 half-tile = 2 gld_lds per phase) leads consumption by 4-6
// phases; s_waitcnt vmcnt(4) ONLY at phases 3 and 7 (VMEM retires in order:
// <=4 outstanding == all older landed == next tile complete). Raw s_barrier
// (no vmcnt drain!) x2 per phase. setprio(1) around MFMA cluster (T5).
// Per-thread vmcnt ledger (steady state, each STAGE = 2 loads): enter iter
// with 4 in flight {A0,B0 of dbuf1-tile}; ph0..3 add 8 -> 12; ph3 WAIT4
// retires oldest 8 -> dbuf1-tile fully in LDS; ph4..7 symmetric -> closes
// invariant. Slot liveness: every slot restaged >=1 closing-barrier after
// its last read. Prologue establishes the invariant; peeled last iter drains.
// Persistent grid 256 (1/CU); epilogue WAIT0 so next tile's counts are exact.
template <int K, int NT, bool GELU, bool GATHER>
__global__ __launch_bounds__(512) void moe_gemm(const u16* __restrict__ Asrc,
                                                const u16* __restrict__ Bsrc,
                                                const float* __restrict__ bias,
                                                const int* __restrict__ list,
                                                const int* __restrict__ counts,
                                                const int* __restrict__ offs,
                                                const int* __restrict__ tmap,
                                                const int* __restrict__ ntiles,
                                                u16* __restrict__ outB,
                                                float* __restrict__ outF) {
    constexpr int NXT = NT / 256;          // n-tiles: 16 (GEMM1) / 4 (GEMM2)
    constexpr int nwg = NXT * MT2;         // 1152 / 288, both %8 == 0
    constexpr int QW = nwg / 8;
    constexpr int ITERS = K / 128;         // 8 (GEMM1) / 32 (GEMM2)
    const int tid = threadIdx.x;
    const int lane = tid & 63;
    const int wv = tid >> 6;               // 0..7
    const int wqr = wv >> 2;               // 64-row strip within quadrant
    const int wqc = wv & 3;                // 32-col strip within quadrant
    const int kq = lane >> 4;
    const int rsub = lane & 15;
    const int rq = kq * 4;
    const int ks1 = tid >> 7;              // my staging k-slice (0..3)
    const int r128 = tid & 127;            // my staging row within a half

    // [dbuf][op A=0/B=1][half][chunk*8]; chunk c = kslice*128 + row (16B each)
    __shared__ u16 Ls[2][2][2][8192];      // 131072 B static LDS, exactly 128 KiB

    const int nw = *ntiles;

#define STAGE_A(db, h, T)                                                   \
    do {                                                                    \
        gld_lds16(aP##h + (T) * 64,      &Ls[db][0][h][tid * 8]);           \
        gld_lds16(aP##h + (T) * 64 + 32, &Ls[db][0][h][(tid + 512) * 8]);   \
    } while (0)
#define STAGE_B(db, h, T)                                                   \
    do {                                                                    \
        gld_lds16(bP##h + (T) * 64,      &Ls[db][1][h][tid * 8]);           \
        gld_lds16(bP##h + (T) * 64 + 32, &Ls[db][1][h][(tid + 512) * 8]);   \
    } while (0)
#define WAIT4 asm volatile("s_waitcnt vmcnt(4)" ::: "memory")
#define WAIT0 asm volatile("s_waitcnt vmcnt(0)" ::: "memory")
#define NOOP ((void)0)

// One phase: frag ds_reads (buffer guaranteed landed by the previous
// counted-wait+barrier), stage one half-tile, barrier, MFMA cluster
// (setprio-wrapped; compiler inserts the lgkmcnt waits for afr/bfr),
// optional counted wait, barrier.
#define PH(db, mh, nh, RDA, STG, WT)                                          \
    do {                                                                      \
        if (RDA) {                                                            \
            _Pragma("unroll") for (int kk = 0; kk < 2; kk++)                  \
            _Pragma("unroll") for (int mi = 0; mi < 4; mi++)                  \
                afr[mi][kk] = *(const short8*)&Ls[db][0][mh]                  \
                    [((kk * 4 + kq) * 128 + wqr * 64 + mi * 16 + rsub) * 8];  \
        }                                                                     \
        _Pragma("unroll") for (int kk = 0; kk < 2; kk++)                      \
        _Pragma("unroll") for (int ni = 0; ni < 2; ni++)                      \
            bfr[ni][kk] = *(const short8*)&Ls[db][1][nh]                      \
                [((kk * 4 + kq) * 128 + wqc * 32 + ni * 16 + rsub) * 8];      \
        STG;                                                                  \
        __builtin_amdgcn_s_barrier();                                         \
        __builtin_amdgcn_s_setprio(1);                                        \
        _Pragma("unroll") for (int mi = 0; mi < 4; mi++)                      \
        _Pragma("unroll") for (int ni = 0; ni < 2; ni++)                      \
        _Pragma("unroll") for (int kk = 0; kk < 2; kk++)                      \
            acc[mh][nh][mi][ni] = __builtin_amdgcn_mfma_f32_16x16x32_bf16(    \
                afr[mi][kk], bfr[ni][kk], acc[mh][nh][mi][ni], 0, 0, 0);      \
        __builtin_amdgcn_s_setprio(0);                                        \
        WT;                                                                   \
        __builtin_amdgcn_s_barrier();                                         \
    } while (0)

#pragma unroll 1
    for (int raw = blockIdx.x; raw < nwg; raw += 256) {
        const int wg = (raw & 7) * QW + (raw >> 3);  // bijective XCD swizzle
        const int nt = wg / MT2;
        const int mt = wg - nt * MT2;
        if (mt >= nw) continue;                      // pad tile (block-uniform)
        const int ent = tmap[mt];
        const int e = ent >> 20;
        const int mbase = ent & 0xFFFFF;
        const int mmax = counts[e] - mbase;          // valid rows (>=1)
        const int rowbase = offs[e] + mbase;
        const int nbase = nt * 256;

        // row indices: direct per-thread loads (no LDS, no extra barrier);
        // results feed the staging addresses, so they retire before STAGE 0.
        size_t arow0, arow1;
        if constexpr (GATHER) {
            arow0 = (size_t)list[e * BT + mbase + min(r128, mmax - 1)];
            arow1 = (size_t)list[e * BT + mbase + min(128 + r128, mmax - 1)];
        } else {
            arow0 = (size_t)(rowbase + min(r128, mmax - 1));
            arow1 = (size_t)(rowbase + min(128 + r128, mmax - 1));
        }
        const u16* aP0 = Asrc + arow0 * (size_t)K + ks1 * 8;
        const u16* aP1 = Asrc + arow1 * (size_t)K + ks1 * 8;
        const u16* bP0 = Bsrc + ((size_t)e * NT + nbase + r128) * (size_t)K + ks1 * 8;
        const u16* bP1 = bP0 + (size_t)128 * K;

        f32x4 acc[2][2][4][2] = {};   // [mh][nh][mi][ni]
        short8 afr[4][2], bfr[2][2];

        // prologue: tile0 (4 halves) -> dbuf0; tile1 A0,B0 -> dbuf1
        STAGE_A(0, 0, 0); STAGE_B(0, 0, 0); STAGE_A(0, 1, 0); STAGE_B(0, 1, 0);
        STAGE_A(1, 0, 1); STAGE_B(1, 0, 1);
        WAIT4;                                   // tile0 landed; tile1 A0,B0 in flight
        __builtin_amdgcn_s_barrier();

#pragma unroll 1
        for (int it = 0; it < ITERS - 1; ++it) {
            const int t = 2 * it;
            PH(0, 0, 0, 1, STAGE_A(1, 1, t + 1), NOOP);
            PH(0, 0, 1, 0, STAGE_B(1, 1, t + 1), NOOP);
            PH(0, 1, 0, 1, STAGE_A(0, 0, t + 2), NOOP);
            PH(0, 1, 1, 0, STAGE_B(0, 0, t + 2), WAIT4);   // tile t+1 landed
            PH(1, 0, 0, 1, STAGE_A(0, 1, t + 2), NOOP);
            PH(1, 0, 1, 0, STAGE_B(0, 1, t + 2), NOOP);
            PH(1, 1, 0, 1, STAGE_A(1, 0, t + 3), NOOP);
            PH(1, 1, 1, 0, STAGE_B(1, 0, t + 3), WAIT4);   // tile t+2 landed
        }
        {   // peeled last iteration: t = 2*ITERS-2; only t+1's A1,B1 remain
            const int t = 2 * (ITERS - 1);
            PH(0, 0, 0, 1, STAGE_A(1, 1, t + 1), NOOP);
            PH(0, 0, 1, 0, STAGE_B(1, 1, t + 1), NOOP);
            PH(0, 1, 0, 1, NOOP, NOOP);
            PH(0, 1, 1, 0, NOOP, WAIT0);                   // tile t+1 fully landed
            PH(1, 0, 0, 1, NOOP, NOOP);
            PH(1, 0, 1, 0, NOOP, NOOP);
            PH(1, 1, 0, 1, NOOP, NOOP);
            PH(1, 1, 1, 0, NOOP, NOOP);
        }

        // epilogue: C/D layout col = lane&15, row = (lane>>4)*4 + reg [m89]
        float bvals[2][2];
#pragma unroll
        for (int nh = 0; nh < 2; nh++)
#pragma unroll
            for (int ni = 0; ni < 2; ni++)
                bvals[nh][ni] = bias[(size_t)e * NT + nbase + nh * 128 + wqc * 32 + ni * 16 + rsub];
#pragma unroll
        for (int mh = 0; mh < 2; mh++) {
#pragma unroll
            for (int mi = 0; mi < 4; mi++) {
#pragma unroll
                for (int r = 0; r < 4; r++) {
                    int m = mh * 128 + wqr * 64 + mi * 16 + rq + r;
                    if (m < mmax) {
                        size_t ro = (size_t)(rowbase + m);
#pragma unroll
                        for (int nh = 0; nh < 2; nh++) {
#pragma unroll
                            for (int ni = 0; ni < 2; ni++) {
                                int n = nbase + nh * 128 + wqc * 32 + ni * 16 + rsub;
                                float v = acc[mh][nh][mi][ni][r] + bvals[nh][ni];
                                if constexpr (GELU) {
                                    v = 0.5f * v * (1.0f + erff(v * 0.7071067811865476f));
                                    outB[ro * NT + n] = f2bf(v);
                                } else {
                                    outF[ro * NT + n] = v;
                                }
                            }
                        }
                    }
                }
            }
        }
        WAIT0;   // drain epilogue stores so next tile's counted vmcnt is exact
    }
#undef PH
#undef STAGE_A
#undef STAGE_B
#undef WAIT4
#undef WAIT0
#undef NOOP
}

// ---------------- softmax over D for both slots + weighted combine + log ----
__global__ void combine_kernel(const float* __restrict__ o, const float* __restrict__ gates,
                               const int* __restrict__ info, const int* __restrict__ offs,
                               float* __restrict__ y) {
    const int b = blockIdx.x;
    const int tid = threadIdx.x;
    const int lane = tid & 63, wv = tid >> 6;
    const int inf0 = info[2 * b], inf1 = info[2 * b + 1];
    const int r0i = offs[inf0 >> 16] + (inf0 & 0xffff);
    const int r1i = offs[inf1 >> 16] + (inf1 & 0xffff);
    const float* r0 = o + (size_t)r0i * DD;
    const float* r1 = o + (size_t)r1i * DD;
    float v0[4], v1[4];
#pragma unroll
    for (int j = 0; j < 4; j++) { v0[j] = r0[tid + 256 * j]; v1[j] = r1[tid + 256 * j]; }
    float m0 = fmaxf(fmaxf(v0[0], v0[1]), fmaxf(v0[2], v0[3]));
    float m1 = fmaxf(fmaxf(v1[0], v1[1]), fmaxf(v1[2], v1[3]));
#pragma unroll
    for (int off = 32; off; off >>= 1) {
        m0 = fmaxf(m0, __shfl_xor(m0, off, 64));
        m1 = fmaxf(m1, __shfl_xor(m1, off, 64));
    }
    __shared__ float sred[2][4];
    if (lane == 0) { sred[0][wv] = m0; sred[1][wv] = m1; }
    __syncthreads();
    m0 = fmaxf(fmaxf(sred[0][0], sred[0][1]), fmaxf(sred[0][2], sred[0][3]));
    m1 = fmaxf(fmaxf(sred[1][0], sred[1][1]), fmaxf(sred[1][2], sred[1][3]));
    float p0[4], p1[4], s0 = 0.f, s1 = 0.f;
#pragma unroll
    for (int j = 0; j < 4; j++) {
        p0[j] = expf(v0[j] - m0); s0 += p0[j];
        p1[j] = expf(v1[j] - m1); s1 += p1[j];
    }
#pragma unroll
    for (int off = 32; off; off >>= 1) {
        s0 += __shfl_xor(s0, off, 64);
        s1 += __shfl_xor(s1, off, 64);
    }
    __shared__ float sred2[2][4];
    if (lane == 0) { sred2[0][wv] = s0; sred2[1][wv] = s1; }
    __syncthreads();
    s0 = sred2[0][0] + sred2[0][1] + sred2[0][2] + sred2[0][3];
    s1 = sred2[1][0] + sred2[1][1] + sred2[1][2] + sred2[1][3];
    const float c0 = gates[2 * b] / s0;
    const float c1 = gates[2 * b + 1] / s1;
#pragma unroll
    for (int j = 0; j < 4; j++) {
        float c = p0[j] * c0 + p1[j] * c1;
        if (c == 0.f) c = 2.2204460492503131e-16f;  // np.finfo(float64).eps
        y[(size_t)b * DD + tid + 256 * j] = logf(c);
    }
}

extern "C" void kernel_launch(void* const* d_in, const int* in_sizes, int n_in,
                              void* d_out, int out_size, void* d_ws, size_t ws_size,
                              hipStream_t stream) {
    const float* x     = (const float*)d_in[0];
    const float* wgate = (const float*)d_in[1];
    const float* fc1w  = (const float*)d_in[2];
    const float* fc1b  = (const float*)d_in[3];
    const float* fc2w  = (const float*)d_in[4];
    const float* fc2b  = (const float*)d_in[5];
    float* out = (float*)d_out;

    char* ws = (char*)d_ws;
    const size_t MB = 1024 * 1024;
    // big layout (289 MiB): [0,64) w1b (later o fp32, exactly 64 MiB)
    //                       [64,128) w2b; [128,256) h bf16 packed; [256,288) xg; meta@288
    // small layout (273 MiB): [0,64) w1b/o; [64,128) w2b; [128,144) xb; [144,272) h; meta@272
    const bool big = ws_size >= 289 * MB;
    u16* w1b = (u16*)(ws);
    float* o = (float*)(ws);
    u16* w2b = (u16*)(ws + 64 * MB);
    u16* xb  = (u16*)(ws + 128 * MB);              // small path only
    u16* h   = (u16*)(ws + (big ? 128 : 144) * MB);
    u16* xg  = (u16*)(ws + 256 * MB);              // big path only
    char* meta = ws + (big ? 288 : 272) * MB;
    int* counts       = (int*)meta;                 // 32 B
    int* offs         = (int*)(meta + 32);          // 32 B
    float* importance = (float*)(meta + 64);        // 32 B
    int* ntiles       = (int*)(meta + 96);          // 4 B (written by loss_kernel)
    float* gate_arr   = (float*)(meta + 128);       // 64 KiB
    int* info         = (int*)(meta + 128 + 65536); // 64 KiB
    int* list         = (int*)(meta + 128 + 131072);// 256 KiB
    int* tmap         = (int*)(meta + 512 * 1024);  // 288 B

    hipMemsetAsync(meta, 0, 96, stream);  // counts + offs + importance
    cvt_kernel<<<(EE * HH * DD / 8 + 255) / 256, 256, 0, stream>>>(fc1w, w1b, EE * HH * DD / 8);
    cvt_kernel<<<(EE * DD * HH / 8 + 255) / 256, 256, 0, stream>>>(fc2w, w2b, EE * DD * HH / 8);
    gating_kernel<<<BT / 4, 256, 0, stream>>>(x, wgate, gate_arr, list, info, counts, importance);
    loss_kernel<<<1, 64, 0, stream>>>(counts, importance, offs, out + (size_t)BT * DD, tmap, ntiles);

    if (big) {
        gather_x_kernel<<<2 * BT, 256, 0, stream>>>(x, list, counts, offs, xg);
        moe_gemm<DD, HH, true, false><<<256, 512, 0, stream>>>(
            xg, w1b, fc1b, nullptr, counts, offs, tmap, ntiles, h, nullptr);
    } else {
        cvt_kernel<<<(BT * DD / 8 + 255) / 256, 256, 0, stream>>>(x, xb, BT * DD / 8);
        moe_gemm<DD, HH, true, true><<<256, 512, 0, stream>>>(
            xb, w1b, fc1b, list, counts, offs, tmap, ntiles, h, nullptr);
    }
    // pass B: o = h @ fc2_w^T + fc2_b ; A rows contiguous (packed), o packed.
    moe_gemm<HH, DD, false, false><<<256, 512, 0, stream>>>(
        h, w2b, fc2b, nullptr, counts, offs, tmap, ntiles, nullptr, o);
    combine_kernel<<<BT, 256, 0, stream>>>(o, gate_arr, info, offs, out);
}